// Round 22
// baseline (515.914 us; speedup 1.0000x reference)
//
#include <hip/hip_runtime.h>
#include <hip/hip_bf16.h>

typedef __hip_bfloat16 bf16;
typedef __attribute__((ext_vector_type(4))) float f32x4;
typedef __attribute__((ext_vector_type(8))) short bf16x8;

__device__ __forceinline__ float b2f(bf16 v){ return __bfloat162float(v); }
__device__ __forceinline__ bf16  f2b(float v){ return __float2bfloat16(v); }
// fast erf (Abramowitz-Stegun 7.1.26, max abs err 1.5e-7) with HW rcp/exp
__device__ __forceinline__ float erf_fast(float x){
  const float ax=fabsf(x);
  const float t=__builtin_amdgcn_rcpf(1.f+0.3275911f*ax);
  const float p=t*(0.254829592f+t*(-0.284496736f+t*(1.421413741f+t*(-1.453152027f+t*1.061405429f))));
  const float r=1.f-p*__expf(-ax*ax);
  return copysignf(r,x);
}
__device__ __forceinline__ float geluf(float x){ return 0.5f*x*(1.0f+erf_fast(x*0.70710678118654752f)); }
__device__ __forceinline__ float lreluf(float x){ return x>0.f? x : 0.01f*x; }
__device__ __forceinline__ float bflo(unsigned u){ return __builtin_bit_cast(float,(unsigned)((u&0xFFFFu)<<16)); }
__device__ __forceinline__ float bfhi(unsigned u){ return __builtin_bit_cast(float,(unsigned)(u&0xFFFF0000u)); }
__device__ __forceinline__ unsigned packbf(float a, float b){
  bf16 ha=f2b(a), hb=f2b(b);
  return (unsigned)__builtin_bit_cast(unsigned short,ha) | ((unsigned)__builtin_bit_cast(unsigned short,hb)<<16);
}

__device__ __forceinline__ int detect_bf16(const unsigned int* words){
  int hits=0;
  for(int i=0;i<64;i++){
    unsigned u=words[i], lo=u&0xFFFFu, e=(lo>>7)&0xFFu;
    if(lo==0u || (e>=100u && e<=140u)) hits++;
  }
  return (hits>=40)?1:0;
}

// fused: dtype-detect (local, deterministic) + convert floats (blocks<28) + zero region (blocks>=28)
struct ConvertArgs { const void* src[28]; float* dst[28]; int n[28]; };
__global__ __launch_bounds__(256) void k_convert(ConvertArgs A, const unsigned int* embw,
                                                 int* flag, float* zp, int zn){
  const int id=blockIdx.x;
  if(id<28){
    const int bf=detect_bf16(embw);
    if(id==0 && threadIdx.x==0) *flag=bf;
    const void* s=A.src[id];
    float* d=A.dst[id];
    const int n=A.n[id];
    if(bf){
      const bf16* sp=(const bf16*)s;
      for(int i=threadIdx.x;i<n;i+=256) d[i]=b2f(sp[i]);
    } else {
      const float* sp=(const float*)s;
      for(int i=threadIdx.x;i<n;i+=256) d[i]=sp[i];
    }
  } else {
    const int zb=id-28;
    int i=zb*256+threadIdx.x;
    const int stride=1024*256;
    for(;i<zn;i+=stride) zp[i]=0.f;
  }
}

struct GemmTasks5 { const float* X[5]; const float* W[5]; float* Y[5]; };

template<int K>
__global__ __launch_bounds__(256) void k_rowgemm(GemmTasks5 T5, int rows, int mode, int xPacked,
    const float* stS, const float* stQ, float invRows,
    const float* gam, const float* bet,
    float* outS, float* outQ, unsigned* Yp, const float* partsIn)
{
  constexpr int KH = K/2;
  const int task = blockIdx.y;
  const float* Xv = T5.X[task];
  const float* W  = T5.W[task];
  float* Y = T5.Y[task];
  const int tid = threadIdx.x, c = tid & 127, kh = tid >> 7;
  __shared__ float redSQ[256];
  if(mode==1 && partsIn){
    float s=0.f;
    for(int k=0;k<64;k++) s+=partsIn[k*256+tid];
    redSQ[tid]=s;
    __syncthreads();
  }
  float wreg[KH];
  #pragma unroll
  for(int i=0;i<KH;i++) wreg[i]=W[(kh*KH+i)*128+c];
  __shared__ float xls[8*K];
  __shared__ float part[2*8*128];
  float ls=0.f, lq=0.f;
  const int nbatch=(rows+7)>>3;
  for (int b=blockIdx.x; b<nbatch; b+=gridDim.x){
    const int base=b*8;
    for (int idx=tid; idx<8*K; idx+=256){
      const int row=idx/K, k=idx-row*K, r=base+row;
      float v=0.f;
      if (r<rows){
        if(xPacked){
          const unsigned u=((const unsigned*)Xv)[(size_t)r*(K/2)+(k>>1)];
          v = (k&1) ? bfhi(u) : bflo(u);
        } else {
          v = Xv[(size_t)r*K+k];
        }
        if (mode==1){
          const float sv = partsIn ? redSQ[k]     : stS[k];
          const float qv = partsIn ? redSQ[128+k] : stQ[k];
          float mn=sv*invRows;
          float vr=fmaxf(qv*invRows-mn*mn,0.f);
          float sc=gam[k]*rsqrtf(vr+1e-5f);
          float sh=bet[k]-mn*sc;
          v=geluf(v*sc+sh);
        }
      }
      xls[idx]=v;
    }
    __syncthreads();
    #pragma unroll
    for (int rr=0;rr<8;rr++){
      const float* xp=&xls[rr*K+kh*KH];
      float acc=0.f;
      #pragma unroll
      for (int j=0;j<KH;j+=4){
        const float4 xv=*(const float4*)(xp+j);
        acc += wreg[j]*xv.x + wreg[j+1]*xv.y + wreg[j+2]*xv.z + wreg[j+3]*xv.w;
      }
      part[kh*1024 + rr*128 + c]=acc;
    }
    __syncthreads();
    if (Yp==nullptr){
      #pragma unroll
      for (int q=0;q<4;q++){
        const int r=kh*4+q, row=base+r;
        if (row<rows){
          float y=part[r*128+c]+part[1024+r*128+c];
          Y[row*128+c]=y;
          ls+=y; lq+=y*y;
        }
      }
      __syncthreads();
    } else {
      if constexpr (K==128){
        #pragma unroll
        for (int q=0;q<4;q++){
          const int r=kh*4+q, row=base+r;
          float y=0.f;
          if (row<rows){
            y=part[r*128+c]+part[1024+r*128+c];
            ls+=y; lq+=y*y;
          }
          xls[r*128+c]=y;
        }
        __syncthreads();
        for (int idx=tid; idx<512; idx+=256){
          const int r2=idx>>6, j=idx&63, row=base+r2;
          if(row<rows) Yp[(size_t)row*64+j]=packbf(xls[r2*128+2*j],xls[r2*128+2*j+1]);
        }
        __syncthreads();
      }
    }
  }
  if (outS){ atomicAdd(&outS[c],ls); atomicAdd(&outQ[c],lq); }
}

// dual-task rowgemm v6: bf16 MFMA (round-16 proven). 256 threads = 4 waves;
// M-tile 16 rows; wave owns 2 column-tiles (B fragments register-resident).
// Both inputs bf16-packed (bm packed in k_bondcyc since round-20).
struct RGDual {
  const float* x0; int rows0; int pk0; float inv0; const float* g0; const float* b0;
  unsigned* yp0; const float* parts0;
  const float* x1; int rows1; int pk1; float inv1; const float* g1; const float* b1;
  unsigned* yp1; const float* parts1;
  const float* W;
};
__global__ __launch_bounds__(256) void k_rowgemm_dual(RGDual D)
{
  const int tid=threadIdx.x;
  const int lane=tid&63, wave=tid>>6;
  const int l15=lane&15, lhi=lane>>4;
  __shared__ float scs0[128], shs0[128], scs1[128], shs1[128];
  {
    const int t=tid>>7, k=tid&127;
    const float* partsIn = t ? D.parts1 : D.parts0;
    float s=0.f,q=0.f;
    for(int j=0;j<64;j++){ s+=partsIn[j*256+k]; }
    for(int j=0;j<64;j++){ q+=partsIn[j*256+128+k]; }
    const float invRows = t ? D.inv1 : D.inv0;
    const float gam = (t ? D.g1 : D.g0)[k];
    const float bet = (t ? D.b1 : D.b0)[k];
    const float mn=s*invRows;
    const float vr=fmaxf(q*invRows-mn*mn,0.f);
    const float sc=gam*rsqrtf(vr+1e-5f);
    const float sh=bet-mn*sc;
    if(t){ scs1[k]=sc; shs1[k]=sh; } else { scs0[k]=sc; shs0[k]=sh; }
  }
  // B fragments (W = Wl, 64KB, L2-resident): load once per block.
  bf16x8 breg[2][4];
  #pragma unroll
  for(int ct=0;ct<2;ct++){
    const int col=(wave*2+ct)*16 + l15;
    #pragma unroll
    for(int ks=0;ks<4;ks++){
      const int kb=ks*32 + lhi*8;
      #pragma unroll
      for(int i=0;i<8;i++){
        breg[ct][ks][i]=__builtin_bit_cast(short, f2b(D.W[(size_t)(kb+i)*128+col]));
      }
    }
  }
  __syncthreads();
  __shared__ short xtile[16*136];   // pad 128->136: 16B-aligned rows, conflict-free A reads
  const int TB0=(D.rows0+15)>>4, TB1=(D.rows1+15)>>4;
  const int TBT=TB0+TB1;
  for (int gb=blockIdx.x; gb<TBT; gb+=gridDim.x){
    const int t1=(gb>=TB0);
    const int b = t1 ? gb-TB0 : gb;
    const float* Xv = t1 ? D.x1 : D.x0;
    const int rows  = t1 ? D.rows1 : D.rows0;
    const int xPacked = t1 ? D.pk1 : D.pk0;
    unsigned* Yp = t1 ? D.yp1 : D.yp0;
    const float* scs = t1 ? scs1 : scs0;
    const float* shs = t1 ? shs1 : shs0;
    const int base=b*16;
    // fill 16x128 bf16 tile (BN+gelu fused, pair-packed u32 stores)
    for (int idx=tid; idx<1024; idx+=256){
      const int row=idx>>6, kp=idx&63, k0=kp*2, r=base+row;
      float v0=0.f,v1=0.f;
      if (r<rows){
        if(xPacked){
          const unsigned u=((const unsigned*)Xv)[(size_t)r*64+kp];
          v0=bflo(u); v1=bfhi(u);
        } else {
          const float2 xv=((const float2*)(Xv+(size_t)r*128))[kp];
          v0=xv.x; v1=xv.y;
        }
        v0=geluf(v0*scs[k0]+shs[k0]);
        v1=geluf(v1*scs[k0+1]+shs[k0+1]);
      }
      ((unsigned*)xtile)[row*68+kp]=packbf(v0,v1);
    }
    __syncthreads();
    f32x4 acc0={0.f,0.f,0.f,0.f}, acc1={0.f,0.f,0.f,0.f};
    #pragma unroll
    for(int ks=0;ks<4;ks++){
      const bf16x8 afrag = *reinterpret_cast<const bf16x8*>(&xtile[l15*136 + ks*32 + lhi*8]);
      acc0=__builtin_amdgcn_mfma_f32_16x16x32_bf16(afrag,breg[0][ks],acc0,0,0,0);
      acc1=__builtin_amdgcn_mfma_f32_16x16x32_bf16(afrag,breg[1][ks],acc1,0,0,0);
    }
    // D write: lane col=(wave*2+ct)*16+l15, rows base+lhi*4+j; pack col pairs via shfl
    #pragma unroll
    for(int j=0;j<4;j++){
      const int row=base+lhi*4+j;
      const float ya=acc0[j];
      const float ya2=__shfl_xor(ya,1,64);
      if(((lane&1)==0) && row<rows)
        Yp[(size_t)row*64 + (wave*2+0)*8 + (l15>>1)]=packbf(ya,ya2);
      const float yb=acc1[j];
      const float yb2=__shfl_xor(yb,1,64);
      if(((lane&1)==0) && row<rows)
        Yp[(size_t)row*64 + (wave*2+1)*8 + (l15>>1)]=packbf(yb,yb2);
    }
    __syncthreads();
  }
}

__global__ __launch_bounds__(256) void k_table_T(const float* emb, const float* w1, const float* b1,
                                                 const float* w2, const float* b2, float* T)
{
  __shared__ float A[2048];
  const int tid=threadIdx.x;
  for (int idx=tid; idx<2048; idx+=256){
    const int half=idx>>10, rem=idx&1023, s=rem>>7, j=rem&127;
    float acc=0.f;
    for(int k=0;k<64;k++) acc += emb[s*64+k]*w1[(half*64+k)*128+j];
    A[idx]=acc;
  }
  __syncthreads();
  const int o=tid&127;
  for(int rr=tid>>7; rr<8; rr+=2){
    const int r=blockIdx.x*8+rr, s=r>>3, d=r&7;
    float acc=b2[o];
    for(int j=0;j<128;j++){
      float t1=A[s*128+j]+A[1024+d*128+j]+b1[j];
      acc+=t1*w2[j*128+o];
    }
    T[r*128+o]=acc;
  }
}

#define SCH 1024

__global__ __launch_bounds__(256) void k_edge_code(const int* sx, const int* src, const int* dst,
    const int* batch, unsigned char* code, unsigned short* gg, int* cnt64, int* ns,
    int* blockHist, int E)
{
  __shared__ int hist[64];
  __shared__ int gh[512];
  const int tid=threadIdx.x;
  if(tid<64) hist[tid]=0;
  for(int i=tid;i<512;i+=256) gh[i]=0;
  __syncthreads();
  const int base=blockIdx.x*SCH;
  #pragma unroll
  for(int u=0;u<SCH/256;u++){
    const int e=base+u*256+tid;
    if(e<E){
      const int s_=src[e], d_=dst[e];
      const int sc=sx[s_], dc=sx[d_];
      const int cd=sc*8+dc;
      code[e]=(unsigned char)cd;
      const int gb=batch[s_];
      gg[e]=(unsigned short)gb;
      atomicAdd(&hist[cd],1);
      atomicAdd(&ns[d_*8+sc],1);
      atomicAdd(&gh[gb],1);
    }
  }
  __syncthreads();
  if(tid<64){ int h=hist[tid]; if(h) atomicAdd(&cnt64[tid],h); }
  for(int i=tid;i<512;i+=256) blockHist[blockIdx.x*512+i]=gh[i];
}

__global__ __launch_bounds__(256) void k_gscan_col(int* blockHist, int* gtot, int NB){
  const int g=blockIdx.x;
  const int tid=threadIdx.x;
  __shared__ int sd[256];
  int run=0;
  for(int base=0;base<NB;base+=256){
    const int b=base+tid;
    const int v=(b<NB)?blockHist[(size_t)b*512+g]:0;
    sd[tid]=v; __syncthreads();
    for(int d=1;d<256;d<<=1){ int t=(tid>=d)?sd[tid-d]:0; __syncthreads(); sd[tid]+=t; __syncthreads(); }
    const int incl=sd[tid];
    const int tot=sd[255];
    if(b<NB) blockHist[(size_t)b*512+g]=run+incl-v;
    __syncthreads();
    run+=tot;
  }
  if(tid==0) gtot[g]=run;
}

// gscatter with inlined goff (integer scan -> exact). sortedG removed
// (pass2 derives group boundaries from gtot).
__global__ __launch_bounds__(256) void k_gscatter(const unsigned short* gg, const int* blockHist,
    const int* gtot, const unsigned char* code, const int* src, const int* dst,
    int* posE, unsigned long long* recP, int E){
  __shared__ int baseg[512];
  __shared__ int sg[512];
  const int tid=threadIdx.x;
  for(int i=tid;i<512;i+=256) sg[i]=gtot[i];
  __syncthreads();
  for(int d=1;d<512;d<<=1){
    int t0[2];
    for(int i=tid,j=0;i<512;i+=256,j++) t0[j]=(i>=d)?sg[i-d]:0;
    __syncthreads();
    for(int i=tid,j=0;i<512;i+=256,j++) sg[i]+=t0[j];
    __syncthreads();
  }
  for(int i=tid;i<512;i+=256) baseg[i]=blockHist[blockIdx.x*512+i]+sg[i]-gtot[i];
  __syncthreads();
  const int base=blockIdx.x*SCH;
  for(int i=tid;i<SCH;i+=256){
    const int e=base+i;
    if(e<E){
      const int g=gg[e];
      const int p=atomicAdd(&baseg[g],1);
      posE[e]=p;
      recP[p]=(unsigned long long)code[e] | ((unsigned long long)(unsigned)src[e]<<8)
            | ((unsigned long long)(unsigned)dst[e]<<32);
    }
  }
}

__global__ __launch_bounds__(256) void k_htable(const float* T, const int* cnt64,
    const float* g0, const float* beta0, const float* wattb, const float* wattc,
    float* h_table, float* abt, float* act, float* ea, int E)
{
  __shared__ float h[64*132];
  __shared__ float cw[64];
  const int tid=threadIdx.x;
  if(tid<64) cw[tid]=(float)cnt64[tid];
  __syncthreads();
  const int c=tid&127;
  const float invE=1.f/(float)E;
  float s=0.f,q=0.f;
  for(int r2=0;r2<64;r2++){ float v=T[r2*128+c]; float w=cw[r2]; s+=w*v; q+=w*v*v; }
  const float mn=s*invE, vr=fmaxf(q*invE-mn*mn,0.f);
  const float sc=g0[c]*rsqrtf(vr+1e-5f), sh=beta0[c]-mn*sc;
  for(int r=tid>>7; r<64; r+=2){
    float v=geluf(T[r*128+c]*sc+sh);
    h[r*132+c]=v;
    h_table[r*128+c]=v;
  }
  __syncthreads();
  if(tid<64){
    float sb=0.f,scc=0.f;
    for(int k=0;k<128;k++){ float hv=h[tid*132+k]; sb+=hv*wattb[k]; scc+=hv*wattc[k]; }
    const float ab_=lreluf(sb), ac_=lreluf(scc);
    abt[tid]=ab_; act[tid]=ac_;
    float mx=ac_;
    #pragma unroll
    for(int o=1;o<64;o<<=1) mx=fmaxf(mx,__shfl_xor(mx,o,64));
    ea[tid]=expf(ac_-mx);
  }
}

__global__ __launch_bounds__(256) void k_cycle_hist(const int* cseg, const int* cidx,
    const unsigned char* code, const int* posE, int* nsc, int* cntP, int M)
{
  const int base=blockIdx.x*1024+threadIdx.x;
  #pragma unroll
  for(int u=0;u<4;u++){
    const int m=base+u*256;
    if(m<M){
      const int e=cidx[m];
      atomicAdd(&nsc[cseg[m]*64 + (int)code[e]],1);
      atomicAdd(&cntP[posE[e]],1);
    }
  }
}

// Round-21 bondcyc v2 (proven): bond branch two-phase (weights computed once in
// Phase A via 8-lane shfl butterflies; Phase B 8 independent hWb loads x 8 FMA).
// Cyc branch = round-19 MFMA loop.
__global__ __launch_bounds__(256) void k_bondcyc(
    const int* nsc, const float* ea, const float* hWc, unsigned* ucm, float* parts2,
    int NC, int cycBlocks,
    const int* ns, const int* sx, const float* abt, const float* hWb,
    unsigned* bmp, float* parts1, int N)
{
  const int tid=threadIdx.x;
  __shared__ float sS[128], sQ[128];
  if(blockIdx.x<cycBlocks){
    // ------- cyc branch (MFMA, round-19 proven) -------
    const int lane=tid&63, wave=tid>>6;
    const int l15=lane&15, lhi=lane>>4;
    bf16x8 breg[2][2];
    #pragma unroll
    for(int ct=0;ct<2;ct++){
      const int col=(wave*2+ct)*16+l15;
      #pragma unroll
      for(int ks=0;ks<2;ks++){
        const int kb=ks*32+lhi*8;
        #pragma unroll
        for(int i=0;i<8;i++)
          breg[ct][ks][i]=__builtin_bit_cast(short, f2b(hWc[(size_t)(kb+i)*128+col]*ea[kb+i]));
      }
    }
    __shared__ float cnts[16*64];
    __shared__ short atile[16*72];   // pad 64->72 shorts: 2-way conflict (free)
    __shared__ float invcs[16];
    if(tid<128){ sS[tid]=0.f; sQ[tid]=0.f; }
    const float eaL=ea[lane];
    float ls0=0.f,lq0=0.f,ls1=0.f,lq1=0.f;
    const int ntile=(NC+15)>>4;
    for(int b=blockIdx.x;b<ntile;b+=cycBlocks){
      const int base=b*16;
      __syncthreads();  // protect cnts/atile from previous iteration readers
      for(int i=tid;i<1024;i+=256){
        const int seg=base+(i>>6);
        const float v=(seg<NC)?(float)nsc[(size_t)seg*64+(i&63)]:0.f;
        cnts[i]=v;
        atile[(i>>6)*72+(i&63)]=__builtin_bit_cast(short,f2b(v));
      }
      __syncthreads();
      // inline segsum (bit-exact: same per-row butterfly on exact float counts)
      #pragma unroll
      for(int rr2=0;rr2<4;rr2++){
        const int r=wave*4+rr2;
        const float n=cnts[r*64+lane];
        float S=n*eaL, C=n;
        #pragma unroll
        for(int o=1;o<64;o<<=1){ S+=__shfl_xor(S,o,64); C+=__shfl_xor(C,o,64); }
        if(lane==0) invcs[r]=(C>0.f&&S>0.f)?1.f/(S*C):0.f;
      }
      f32x4 acc0={0.f,0.f,0.f,0.f}, acc1={0.f,0.f,0.f,0.f};
      #pragma unroll
      for(int ks=0;ks<2;ks++){
        const bf16x8 afrag=*reinterpret_cast<const bf16x8*>(&atile[l15*72+ks*32+lhi*8]);
        acc0=__builtin_amdgcn_mfma_f32_16x16x32_bf16(afrag,breg[0][ks],acc0,0,0,0);
        acc1=__builtin_amdgcn_mfma_f32_16x16x32_bf16(afrag,breg[1][ks],acc1,0,0,0);
      }
      __syncthreads();  // invcs ready for all waves
      #pragma unroll
      for(int j=0;j<4;j++){
        const int r16=lhi*4+j, row=base+r16;
        const float iv=invcs[r16];
        const float y0=acc0[j]*iv;
        const float y1=acc1[j]*iv;
        ls0+=y0; lq0+=y0*y0; ls1+=y1; lq1+=y1*y1;
        const float y0b=__shfl_xor(y0,1,64);
        if(((lane&1)==0) && row<NC)
          ucm[(size_t)row*64 + (wave*2+0)*8 + (l15>>1)]=packbf(y0,y0b);
        const float y1b=__shfl_xor(y1,1,64);
        if(((lane&1)==0) && row<NC)
          ucm[(size_t)row*64 + (wave*2+1)*8 + (l15>>1)]=packbf(y1,y1b);
      }
    }
    __syncthreads();
    const int c0=(wave*2+0)*16+l15, c1=(wave*2+1)*16+l15;
    atomicAdd(&sS[c0],ls0); atomicAdd(&sQ[c0],lq0);
    atomicAdd(&sS[c1],ls1); atomicAdd(&sQ[c1],lq1);
    __syncthreads();
    if(tid<128){
      float* slot=&parts2[(size_t)(blockIdx.x&63)*256];
      atomicAdd(&slot[tid],sS[tid]); atomicAdd(&slot[128+tid],sQ[tid]);
    }
  } else {
    // ------- bond branch v2 (two-phase) -------
    const int base=(blockIdx.x-cycBlocks)*16;
    __shared__ float wts[16*8];
    __shared__ int dcls[16];
    if(tid<16){ const int n=base+tid; dcls[tid]=(n<N)?sx[n]:0; }
    __syncthreads();
    if(tid<128){
      // thread = node*8 + s ; 8-lane groups align within the wave
      const int node=tid>>3, s=tid&7;
      const int n=base+node;
      float v=0.f, a=-1e30f;
      if(n<N){
        v=(float)ns[n*8+s];
        if(v>0.f) a=abt[s*8+dcls[node]];
      }
      float cnt=v, mx=a;
      #pragma unroll
      for(int o=1;o<8;o<<=1){ cnt+=__shfl_xor(cnt,o,64); mx=fmaxf(mx,__shfl_xor(mx,o,64)); }
      const float ex=(v>0.f)? v*expf(a-mx) : 0.f;
      float ssum=ex;
      #pragma unroll
      for(int o=1;o<8;o<<=1) ssum+=__shfl_xor(ssum,o,64);
      float w=0.f;
      if(cnt>0.f){ const float inv=1.f/(ssum*cnt); w=ex*inv; }
      wts[tid]=w;
    }
    __syncthreads();
    const int c=tid&127, grp=tid>>7;
    float ls=0.f,lq=0.f;
    #pragma unroll
    for(int i=0;i<8;i++){
      const int node=grp*8+i;
      const int n=base+node;
      if(n>=N) break;   // wave-uniform
      const int d=dcls[node];
      float y=0.f;
      #pragma unroll
      for(int s=0;s<8;s++){
        const float w=wts[node*8+s];
        if(w>0.f) y += w*hWb[(s*8+d)*128+c];
      }
      const float y2=__shfl_xor(y,1,64);
      if((c&1)==0) bmp[(size_t)n*64+(c>>1)]=packbf(y,y2);
      ls+=y; lq+=y*y;
    }
    if(tid<128){ sS[tid]=0.f; sQ[tid]=0.f; }
    __syncthreads();
    atomicAdd(&sS[c],ls); atomicAdd(&sQ[c],lq);
    __syncthreads();
    if(tid<128){
      float* slot=&parts1[(size_t)(blockIdx.x&63)*256];
      atomicAdd(&slot[tid],sS[tid]); atomicAdd(&slot[128+tid],sQ[tid]);
    }
  }
}

__global__ __launch_bounds__(256) void k_scan_block(const int* cntP, int* blkSum, int E){
  __shared__ int sd[256];
  const int tid=threadIdx.x, base=blockIdx.x*1024;
  int s=0;
  for(int q=0;q<4;q++){ int i=base+tid*4+q; if(i<E) s+=cntP[i]; }
  sd[tid]=s; __syncthreads();
  for(int d=1;d<256;d<<=1){ int t=(tid>=d)?sd[tid-d]:0; __syncthreads(); sd[tid]+=t; __syncthreads(); }
  if(tid==255) blkSum[blockIdx.x]=sd[255];
}

__global__ __launch_bounds__(256) void k_scan_mid(const int* blkSum, int* blkOff, int nb){
  __shared__ int sd[1024];
  const int tid=threadIdx.x;
  for(int i=tid;i<1024;i+=256) sd[i]=(i<nb)?blkSum[i]:0;
  __syncthreads();
  for(int d=1;d<1024;d<<=1){
    int t[4];
    for(int i=tid,j=0;i<1024;i+=256,j++) t[j]=(i>=d)?sd[i-d]:0;
    __syncthreads();
    for(int i=tid,j=0;i<1024;i+=256,j++) sd[i]+=t[j];
    __syncthreads();
  }
  for(int i=tid;i<nb;i+=256) blkOff[i]=sd[i]-blkSum[i];
}

__global__ __launch_bounds__(256) void k_scan_write(const int* cntP, const int* blkOff,
                                                    int* offP, int E, int M){
  __shared__ int sd[256];
  const int tid=threadIdx.x, base=blockIdx.x*1024;
  int v[4]; int s=0;
  for(int q=0;q<4;q++){ int i=base+tid*4+q; v[q]=(i<E)?cntP[i]:0; s+=v[q]; }
  sd[tid]=s; __syncthreads();
  for(int d=1;d<256;d<<=1){ int t=(tid>=d)?sd[tid-d]:0; __syncthreads(); sd[tid]+=t; __syncthreads(); }
  int run=blkOff[blockIdx.x]+sd[tid]-s;
  for(int q=0;q<4;q++){ int i=base+tid*4+q; if(i<E) offP[i]=run; run+=v[q]; }
  if(blockIdx.x==0&&tid==0) offP[E]=M;
}

__global__ __launch_bounds__(256) void k_place(const int* cseg, const int* cidx, const int* posE,
                                               const int* offP, int* cursor, int* entrySeg, int M){
  const int base=blockIdx.x*1024+threadIdx.x;
  #pragma unroll
  for(int u=0;u<4;u++){
    const int m=base+u*256;
    if(m<M){
      const int p=posE[cidx[m]];
      const int pos=offP[p]+atomicAdd(&cursor[p],1);
      entrySeg[pos]=cseg[m];
    }
  }
}

// pass1: gather + stats + bf16 vbuf store. Persistent 2048 blocks; each wave owns a
// CONTIGUOUS edge range (round-4 structure, proven). The sequential packbf store
// (256 B/edge, streaming) hides under the gather latency; pass2 then never gathers.
__global__ __launch_bounds__(256) void k_pass1_store(const unsigned long long* recP,
    const float* eLt, const unsigned* ubond, const unsigned* ucyc,
    const int* offP, const int* entrySeg, unsigned* vbuf, float* parts,
    int E, int upx)
{
  const int tid=threadIdx.x;
  const int lane=tid&63, wave=tid>>6;
  const int xcd=blockIdx.x&7;
  const int wix=(blockIdx.x>>3)*4+wave;   // 0..1023 within xcd
  const int NU=(E+15)>>4;
  int u0=xcd*upx + (int)(((long long)wix*(long long)upx)>>10);
  int u1=xcd*upx + (int)(((long long)(wix+1)*(long long)upx)>>10);
  if(u0>NU)u0=NU; if(u1>NU)u1=NU;
  int e=u0*16; const int e1=(u1*16<E)?u1*16:E;
  float lsx=0.f,lsy=0.f,lqx=0.f,lqy=0.f;
  while(e<e1){
    int nv=e1-e; if(nv>64)nv=64;
    const int t=e+((lane<nv)?lane:(nv-1));
    const unsigned long long r0=recP[t];
    const unsigned rlo=(unsigned)r0, rhi=(unsigned)(r0>>32);
    const int oa0=offP[t], ob0=offP[t+1];
    int i=0;
    for(; i+8<=nv; i+=8){
      unsigned lo[8],hi[8]; int a[8],b[8];
      #pragma unroll
      for(int q=0;q<8;q++){
        lo[q]=(unsigned)__builtin_amdgcn_readlane((int)rlo,i+q);
        hi[q]=(unsigned)__builtin_amdgcn_readlane((int)rhi,i+q);
        a[q]=__builtin_amdgcn_readlane(oa0,i+q);
        b[q]=__builtin_amdgcn_readlane(ob0,i+q);
      }
      float2 ea[8]; unsigned ub[8],ud[8];
      #pragma unroll
      for(int q=0;q<8;q++){
        ea[q]=((const float2*)(eLt+(size_t)(lo[q]&0xFFu)*128))[lane];
        ub[q]=ubond[(size_t)(lo[q]>>8)*64+lane];
        ud[q]=ubond[(size_t)hi[q]*64+lane];
      }
      #pragma unroll
      for(int q=0;q<8;q++){
        float x=ea[q].x+bflo(ub[q])+bflo(ud[q]);
        float y=ea[q].y+bfhi(ub[q])+bfhi(ud[q]);
        for(int j=a[q];j<b[q];j++){
          const unsigned w=ucyc[(size_t)entrySeg[j]*64+lane];
          x+=bflo(w); y+=bfhi(w);
        }
        lsx+=x; lqx+=x*x; lsy+=y; lqy+=y*y;
        vbuf[(size_t)(e+i+q)*64+lane]=packbf(x,y);
      }
    }
    for(; i<nv; i++){
      const unsigned lo=(unsigned)__builtin_amdgcn_readlane((int)rlo,i);
      const unsigned hi=(unsigned)__builtin_amdgcn_readlane((int)rhi,i);
      const int a=__builtin_amdgcn_readlane(oa0,i);
      const int b=__builtin_amdgcn_readlane(ob0,i);
      const float2 ea2=((const float2*)(eLt+(size_t)(lo&0xFFu)*128))[lane];
      const unsigned ub=ubond[(size_t)(lo>>8)*64+lane];
      const unsigned ud=ubond[(size_t)hi*64+lane];
      float x=ea2.x+bflo(ub)+bflo(ud);
      float y=ea2.y+bfhi(ub)+bfhi(ud);
      for(int j=a;j<b;j++){
        const unsigned w=ucyc[(size_t)entrySeg[j]*64+lane];
        x+=bflo(w); y+=bfhi(w);
      }
      lsx+=x; lqx+=x*x; lsy+=y; lqy+=y*y;
      vbuf[(size_t)(e+i)*64+lane]=packbf(x,y);
    }
    e+=nv;
  }
  __shared__ float sS[128], sQ[128];
  if(tid<128){ sS[tid]=0.f; sQ[tid]=0.f; }
  __syncthreads();
  const int c0=lane*2;
  atomicAdd(&sS[c0],lsx); atomicAdd(&sS[c0+1],lsy);
  atomicAdd(&sQ[c0],lqx); atomicAdd(&sQ[c0+1],lqy);
  __syncthreads();
  if(tid<128){
    float* slot=&parts[(size_t)(blockIdx.x&63)*256];
    atomicAdd(&slot[tid],sS[tid]); atomicAdd(&slot[128+tid],sQ[tid]);
  }
}

// pass2 v3: group-segment iteration (round-18 boundaries-from-gtot) married to
// round-15's proven uint2 half-wave load pattern: lane covers 4 cols (cb=l32*4),
// half-waves process row pairs, 32-row main batch = 16 uint2/lane (128 B/lane in
// flight, half the load instructions of v2's 4B loads). Predicated odd-row tail
// (segment boundaries arbitrary). Summation-order change = same fp-reorder class
// as the accepted round-15 change.
__global__ __launch_bounds__(256) void k_pass2_stream(const uint2* vbuf2,
    const int* gtot, const float* parts,
    const float* g3, const float* beta3, float* gsum, int E)
{
  __shared__ float sSQ[256];
  __shared__ int sg[512];
  __shared__ int goffL[513];
  const int tid=threadIdx.x;
  {
    float s=0.f;
    #pragma unroll 8
    for(int k=0;k<64;k++) s+=parts[k*256+tid];
    sSQ[tid]=s;
  }
  for(int i=tid;i<512;i+=256) sg[i]=gtot[i];
  __syncthreads();
  for(int d=1;d<512;d<<=1){
    int t0[2];
    for(int i=tid,j=0;i<512;i+=256,j++) t0[j]=(i>=d)?sg[i-d]:0;
    __syncthreads();
    for(int i=tid,j=0;i<512;i+=256,j++) sg[i]+=t0[j];
    __syncthreads();
  }
  for(int i=tid;i<512;i+=256) goffL[i]=sg[i]-gtot[i];
  if(tid==0) goffL[512]=E;
  __syncthreads();
  const int lane=tid&63, wave=tid>>6;
  const int half=lane>>5, l32=lane&31;
  const int cb=l32*4;
  const float invE=1.f/(float)E;
  float sc[4],sh[4];
  #pragma unroll
  for(int k2=0;k2<4;k2++){
    const int c=cb+k2;
    float mn=sSQ[c]*invE, vr=fmaxf(sSQ[128+c]*invE-mn*mn,0.f);
    sc[k2]=g3[c]*rsqrtf(vr+1e-5f); sh[k2]=beta3[c]-mn*sc[k2];
  }
  const int wix=blockIdx.x*4+wave;      // 0..8191
  int i0=(int)(((long long)wix*(long long)E)>>13);
  int i1=(int)(((long long)(wix+1)*(long long)E)>>13);
  if(i1>E)i1=E;
  if(i0>=i1) return;
  // binary search: largest g with goffL[g] <= i0
  int glo=0, ghi=512;
  while(glo+1<ghi){ const int gm=(glo+ghi)>>1; if(goffL[gm]<=i0) glo=gm; else ghi=gm; }
  int g=glo;
  int i=i0;
  while(i<i1){
    const int segEnd = (goffL[g+1]<i1)?goffL[g+1]:i1;
    if(segEnd<=i){ g++; continue; }
    float a0=0.f,a1=0.f,a2=0.f,a3=0.f;
    for(; i+32<=segEnd; i+=32){
      uint2 uq[16];
      #pragma unroll
      for(int q=0;q<16;q++) uq[q]=vbuf2[(size_t)(i+2*q+half)*32+l32];
      #pragma unroll
      for(int q=0;q<16;q++){
        a0+=geluf(fmaf(bflo(uq[q].x),sc[0],sh[0]));
        a1+=geluf(fmaf(bfhi(uq[q].x),sc[1],sh[1]));
        a2+=geluf(fmaf(bflo(uq[q].y),sc[2],sh[2]));
        a3+=geluf(fmaf(bfhi(uq[q].y),sc[3],sh[3]));
      }
    }
    for(; i+8<=segEnd; i+=8){
      uint2 uq[4];
      #pragma unroll
      for(int q=0;q<4;q++) uq[q]=vbuf2[(size_t)(i+2*q+half)*32+l32];
      #pragma unroll
      for(int q=0;q<4;q++){
        a0+=geluf(fmaf(bflo(uq[q].x),sc[0],sh[0]));
        a1+=geluf(fmaf(bfhi(uq[q].x),sc[1],sh[1]));
        a2+=geluf(fmaf(bflo(uq[q].y),sc[2],sh[2]));
        a3+=geluf(fmaf(bfhi(uq[q].y),sc[3],sh[3]));
      }
    }
    for(; i+2<=segEnd; i+=2){
      const uint2 u=vbuf2[(size_t)(i+half)*32+l32];
      a0+=geluf(fmaf(bflo(u.x),sc[0],sh[0]));
      a1+=geluf(fmaf(bfhi(u.x),sc[1],sh[1]));
      a2+=geluf(fmaf(bflo(u.y),sc[2],sh[2]));
      a3+=geluf(fmaf(bfhi(u.y),sc[3],sh[3]));
    }
    if(i<segEnd){            // odd last row of segment: half 0 only
      if(half==0){
        const uint2 u=vbuf2[(size_t)i*32+l32];
        a0+=geluf(fmaf(bflo(u.x),sc[0],sh[0]));
        a1+=geluf(fmaf(bfhi(u.x),sc[1],sh[1]));
        a2+=geluf(fmaf(bflo(u.y),sc[2],sh[2]));
        a3+=geluf(fmaf(bfhi(u.y),sc[3],sh[3]));
      }
      i++;
    }
    atomicAdd(&gsum[g*128+cb+0],a0); atomicAdd(&gsum[g*128+cb+1],a1);
    atomicAdd(&gsum[g*128+cb+2],a2); atomicAdd(&gsum[g*128+cb+3],a3);
    g++;
  }
}

__global__ __launch_bounds__(256) void k_out(const float* gw, const float* st4S, const float* st4Q,
    const float* g4, const float* beta4, const float* wout, void* out, const int* flag, int G)
{
  const int lane=threadIdx.x&63;
  const int r=blockIdx.x*4 + (threadIdx.x>>6);
  const float invG=1.f/(float)G;
  float a0=0.f,a1=0.f;
  #pragma unroll
  for(int h=0;h<2;h++){
    const int k=lane+64*h;
    const float mn=st4S[k]*invG;
    const float vr=fmaxf(st4Q[k]*invG-mn*mn,0.f);
    const float sc=g4[k]*rsqrtf(vr+1e-5f), sh=beta4[k]-mn*sc;
    const float v=geluf(gw[r*128+k]*sc+sh);
    a0+=v*wout[k*2+0]; a1+=v*wout[k*2+1];
  }
  for(int o=1;o<64;o<<=1){ a0+=__shfl_xor(a0,o,64); a1+=__shfl_xor(a1,o,64); }
  if(lane==0){
    if(*flag){ ((bf16*)out)[r*2+0]=f2b(a0); ((bf16*)out)[r*2+1]=f2b(a1); }
    else     { ((float*)out)[r*2+0]=a0;     ((float*)out)[r*2+1]=a1; }
  }
}

extern "C" void kernel_launch(void* const* d_in, const int* in_sizes, int n_in,
                              void* d_out, int out_size, void* d_ws, size_t ws_size,
                              hipStream_t stream)
{
  const int N  = in_sizes[0];
  const int E  = in_sizes[1]/2;
  const int M  = in_sizes[3];
  const int NC = 50000;
  const int G  = 512;

  const int* sub_x=(const int*)d_in[0];
  const int* src=(const int*)d_in[1];
  const int* dst=src+E;
  const int* batch=(const int*)d_in[2];
  const int* cseg=(const int*)d_in[3];
  const int* cidx=(const int*)d_in[4];

  char* ws=(char*)d_ws;
  size_t off=0;
  auto carve=[&](size_t bytes)->char*{ char* p=ws+off; off=(off+bytes+255)&~(size_t)255; return p; };

  size_t ftot=0;
  for(int i=0;i<28;i++) ftot += (size_t)in_sizes[5+i];
  float* stage=(float*)carve(ftot*4);
  float* fin[28];
  { size_t so=0; for(int i=0;i<28;i++){ fin[i]=stage+so; so+=(size_t)in_sizes[5+i]; } }
  const float *emb_f=fin[0], *w1_f=fin[1], *b1_f=fin[2], *w2_f=fin[3], *b2_f=fin[4],
              *g0_f=fin[5], *beta0_f=fin[6], *wattb_f=fin[7], *wb1_f=fin[8], *wb2_f=fin[9],
              *g1_f=fin[10], *beta1_f=fin[11], *wattc_f=fin[12], *wc1_f=fin[13], *wc2_f=fin[14],
              *g2_f=fin[15], *beta2_f=fin[16], *we1_f=fin[17], *we2_f=fin[18], *wl1_f=fin[19],
              *wl2_f=fin[20], *g3_f=fin[21], *beta3_f=fin[22], *wg1_f=fin[23], *wg2_f=fin[24],
              *g4_f=fin[25], *beta4_f=fin[26], *wout_f=fin[27];

  int* flag=(int*)carve(256);
  float* Wb =(float*)carve(65536);
  float* Wc =(float*)carve(65536);
  float* Wl =(float*)carve(65536);
  float* Wg =(float*)carve(65536);
  float* We =(float*)carve(65536);
  float* Wel=(float*)carve(65536);
  float* T      =(float*)carve(64*128*4);
  float* h_table=(float*)carve(64*128*4);
  float* hWb    =(float*)carve(64*128*4);
  float* hWc    =(float*)carve(64*128*4);
  float* eLt    =(float*)carve(64*128*4);
  float* abt=(float*)carve(256);
  float* act=(float*)carve(256);
  float* eaT=(float*)carve(256);
  unsigned* bmp =(unsigned*)carve((size_t)N*64*4);   // bond output, bf16-packed
  unsigned* ucm=(unsigned*)carve((size_t)NC*64*4);
  unsigned* ubond=(unsigned*)carve((size_t)N*64*4);
  unsigned* ucyc =(unsigned*)carve((size_t)NC*64*4);
  unsigned char* code=(unsigned char*)carve((size_t)E);
  unsigned short* gg=(unsigned short*)carve((size_t)E*2);
  int*   posE  =(int*)carve((size_t)E*4);
  unsigned long long* recP=(unsigned long long*)carve((size_t)E*8);
  int*   offP  =(int*)carve((size_t)(E+1)*4);
  int*   entrySeg=(int*)carve((size_t)M*4);
  int*   blkSum=(int*)carve(4096);
  int*   blkOff=(int*)carve(4096);
  int*   gtot  =(int*)carve(2048);
  const int NB=(E+SCH-1)/SCH;
  int*   blockHist=(int*)carve((size_t)NB*512*4);
  float* gw  =(float*)carve((size_t)G*128*4);

  const size_t zStart=off;
  int*   cnt64=(int*)carve(256);
  float* stats=(float*)carve(4096);
  float* st4S=stats+6*128, *st4Q=stats+7*128;
  float* parts1=(float*)carve(64*256*4);
  float* parts2=(float*)carve(64*256*4);
  float* parts3=(float*)carve(64*256*4);
  float* gsum=(float*)carve((size_t)G*128*4);
  int*   ns   =(int*)carve((size_t)N*8*4);
  int*   nsc  =(int*)carve((size_t)NC*64*4);
  int*   cntP =(int*)carve((size_t)E*4);
  int*   cursor=(int*)carve((size_t)E*4);
  const size_t zEnd=off;

  // big bf16 v-row buffer LAST (graph-sorted order)
  unsigned* vbuf=(unsigned*)carve((size_t)E*64*4);
  const int haveV = (off <= ws_size) ? 1 : 0;
  (void)n_in; (void)out_size;

  // 0. fused detect + convert + zero
  {
    ConvertArgs A{};
    for(int i=0;i<28;i++){ A.src[i]=d_in[5+i]; A.dst[i]=fin[i]; A.n[i]=in_sizes[5+i]; }
    k_convert<<<28+1024,256,0,stream>>>(A,(const unsigned int*)d_in[5],flag,
                                        (float*)(ws+zStart),(int)((zEnd-zStart)/4));
  }

  // 2. h pre-activation table
  k_table_T<<<8,256,0,stream>>>(emb_f,w1_f,b1_f,w2_f,b2_f,T);

  // 3. weight products
  {
    GemmTasks5 t{};
    t.X[0]=wb1_f; t.W[0]=wb2_f; t.Y[0]=Wb;
    t.X[1]=wc1_f; t.W[1]=wc2_f; t.Y[1]=Wc;
    t.X[2]=wl1_f; t.W[2]=wl2_f; t.Y[2]=Wl;
    t.X[3]=wg1_f; t.W[3]=wg2_f; t.Y[3]=Wg;
    t.X[4]=we1_f; t.W[4]=we2_f; t.Y[4]=We;
    k_rowgemm<128><<<dim3(16,5),256,0,stream>>>(t,128,0,0,nullptr,nullptr,0.f,nullptr,nullptr,nullptr,nullptr,nullptr,nullptr);
  }
  {
    GemmTasks5 t{};
    t.X[0]=We; t.W[0]=Wl; t.Y[0]=Wel;
    k_rowgemm<128><<<dim3(16,1),256,0,stream>>>(t,128,0,0,nullptr,nullptr,0.f,nullptr,nullptr,nullptr,nullptr,nullptr,nullptr);
  }

  // 4. edge codes + histograms; two-level sort (goff folded into gscatter)
  k_edge_code<<<NB,256,0,stream>>>(sub_x,src,dst,batch,code,gg,cnt64,ns,blockHist,E);
  k_gscan_col<<<512,256,0,stream>>>(blockHist,gtot,NB);
  k_gscatter<<<NB,256,0,stream>>>(gg,blockHist,gtot,code,src,dst,posE,recP,E);
  // 5. h table + attention logits + ea
  k_htable<<<1,256,0,stream>>>(T,cnt64,g0_f,beta0_f,wattb_f,wattc_f,h_table,abt,act,eaT,E);
  // 6. table products
  {
    GemmTasks5 t{};
    t.X[0]=h_table; t.W[0]=Wb;  t.Y[0]=hWb;
    t.X[1]=h_table; t.W[1]=Wc;  t.Y[1]=hWc;
    t.X[2]=h_table; t.W[2]=Wel; t.Y[2]=eLt;
    k_rowgemm<128><<<dim3(8,3),256,0,stream>>>(t,64,0,0,nullptr,nullptr,0.f,nullptr,nullptr,nullptr,nullptr,nullptr,nullptr);
  }
  // 7. cycle histograms (segment normalization folded into the fused cyc branch)
  k_cycle_hist<<<(M+1023)/1024,256,0,stream>>>(cseg,cidx,code,posE,nsc,cntP,M);
  // 8. bond + cycle branches fused in ONE dispatch (independent producers ->
  // machine-level overlap instead of stream serialization).
  {
    const int bondBlocks=(N+15)/16;
    k_bondcyc<<<2048+bondBlocks,256,0,stream>>>(nsc,eaT,hWc,ucm,parts2,NC,2048,
                                                ns,sub_x,abt,hWb,bmp,parts1,N);
  }
  // 9-11. bondL + cycL, one MFMA dispatch, unified balanced tile pool (both
  // inputs bf16-packed).
  {
    RGDual D{};
    D.x0=(const float*)bmp;  D.rows0=N;  D.pk0=1; D.inv0=1.f/(float)N;  D.g0=g1_f; D.b0=beta1_f; D.yp0=ubond; D.parts0=parts1;
    D.x1=(const float*)ucm;  D.rows1=NC; D.pk1=1; D.inv1=1.f/(float)NC; D.g1=g2_f; D.b1=beta2_f; D.yp1=ucyc;  D.parts1=parts2;
    D.W=Wl;
    k_rowgemm_dual<<<2048,256,0,stream>>>(D);
  }
  // 12. CSR over sorted positions
  const int nb=(E+1023)/1024;
  k_scan_block<<<nb,256,0,stream>>>(cntP,blkSum,E);
  k_scan_mid<<<1,256,0,stream>>>(blkSum,blkOff,nb);
  k_scan_write<<<nb,256,0,stream>>>(cntP,blkOff,offP,E,M);
  k_place<<<(M+1023)/1024,256,0,stream>>>(cseg,cidx,posE,offP,cursor,entrySeg,M);
  // 13-14. hybrid: single gather pass (stats + bf16 store), then group-segment
  // stream pool (uint2 half-wave loads, 32-row batches).
  {
    const int NU=(E+15)/16;
    const int upx=(NU+7)/8;
    k_pass1_store<<<2048,256,0,stream>>>(recP,eLt,ubond,ucyc,offP,entrySeg,
                                         haveV?vbuf:(unsigned*)cursor,parts3,E,upx);
    k_pass2_stream<<<2048,256,0,stream>>>((const uint2*)vbuf,gtot,parts3,
                                          g3_f,beta3_f,gsum,E);
  }
  // 15. head
  {
    GemmTasks5 t{};
    t.X[0]=gsum; t.W[0]=Wg; t.Y[0]=gw;
    k_rowgemm<128><<<dim3(64,1),256,0,stream>>>(t,G,0,0,nullptr,nullptr,0.f,nullptr,nullptr,st4S,st4Q,nullptr,nullptr);
  }
  // 16. out
  k_out<<<G/4,256,0,stream>>>(gw,st4S,st4Q,g4_f,beta4_f,wout_f,d_out,flag,G);
}

// Round 23
// 494.539 us; speedup vs baseline: 1.0432x; 1.0432x over previous
//
#include <hip/hip_runtime.h>
#include <hip/hip_bf16.h>

typedef __hip_bfloat16 bf16;
typedef __attribute__((ext_vector_type(4))) float f32x4;
typedef __attribute__((ext_vector_type(8))) short bf16x8;

__device__ __forceinline__ float b2f(bf16 v){ return __bfloat162float(v); }
__device__ __forceinline__ bf16  f2b(float v){ return __float2bfloat16(v); }
// fast erf (Abramowitz-Stegun 7.1.26, max abs err 1.5e-7) with HW rcp/exp
__device__ __forceinline__ float erf_fast(float x){
  const float ax=fabsf(x);
  const float t=__builtin_amdgcn_rcpf(1.f+0.3275911f*ax);
  const float p=t*(0.254829592f+t*(-0.284496736f+t*(1.421413741f+t*(-1.453152027f+t*1.061405429f))));
  const float r=1.f-p*__expf(-ax*ax);
  return copysignf(r,x);
}
__device__ __forceinline__ float geluf(float x){ return 0.5f*x*(1.0f+erf_fast(x*0.70710678118654752f)); }
__device__ __forceinline__ float lreluf(float x){ return x>0.f? x : 0.01f*x; }
__device__ __forceinline__ float bflo(unsigned u){ return __builtin_bit_cast(float,(unsigned)((u&0xFFFFu)<<16)); }
__device__ __forceinline__ float bfhi(unsigned u){ return __builtin_bit_cast(float,(unsigned)(u&0xFFFF0000u)); }
__device__ __forceinline__ unsigned packbf(float a, float b){
  bf16 ha=f2b(a), hb=f2b(b);
  return (unsigned)__builtin_bit_cast(unsigned short,ha) | ((unsigned)__builtin_bit_cast(unsigned short,hb)<<16);
}

__device__ __forceinline__ int detect_bf16(const unsigned int* words){
  int hits=0;
  for(int i=0;i<64;i++){
    unsigned u=words[i], lo=u&0xFFFFu, e=(lo>>7)&0xFFu;
    if(lo==0u || (e>=100u && e<=140u)) hits++;
  }
  return (hits>=40)?1:0;
}

// fused: dtype-detect (local, deterministic) + convert floats (blocks<28) + zero region (blocks>=28)
struct ConvertArgs { const void* src[28]; float* dst[28]; int n[28]; };
__global__ __launch_bounds__(256) void k_convert(ConvertArgs A, const unsigned int* embw,
                                                 int* flag, float* zp, int zn){
  const int id=blockIdx.x;
  if(id<28){
    const int bf=detect_bf16(embw);
    if(id==0 && threadIdx.x==0) *flag=bf;
    const void* s=A.src[id];
    float* d=A.dst[id];
    const int n=A.n[id];
    if(bf){
      const bf16* sp=(const bf16*)s;
      for(int i=threadIdx.x;i<n;i+=256) d[i]=b2f(sp[i]);
    } else {
      const float* sp=(const float*)s;
      for(int i=threadIdx.x;i<n;i+=256) d[i]=sp[i];
    }
  } else {
    const int zb=id-28;
    int i=zb*256+threadIdx.x;
    const int stride=1024*256;
    for(;i<zn;i+=stride) zp[i]=0.f;
  }
}

struct GemmTasks5 { const float* X[5]; const float* W[5]; float* Y[5]; };

template<int K>
__global__ __launch_bounds__(256) void k_rowgemm(GemmTasks5 T5, int rows, int mode, int xPacked,
    const float* stS, const float* stQ, float invRows,
    const float* gam, const float* bet,
    float* outS, float* outQ, unsigned* Yp, const float* partsIn)
{
  constexpr int KH = K/2;
  const int task = blockIdx.y;
  const float* Xv = T5.X[task];
  const float* W  = T5.W[task];
  float* Y = T5.Y[task];
  const int tid = threadIdx.x, c = tid & 127, kh = tid >> 7;
  __shared__ float redSQ[256];
  if(mode==1 && partsIn){
    float s=0.f;
    for(int k=0;k<64;k++) s+=partsIn[k*256+tid];
    redSQ[tid]=s;
    __syncthreads();
  }
  float wreg[KH];
  #pragma unroll
  for(int i=0;i<KH;i++) wreg[i]=W[(kh*KH+i)*128+c];
  __shared__ float xls[8*K];
  __shared__ float part[2*8*128];
  float ls=0.f, lq=0.f;
  const int nbatch=(rows+7)>>3;
  for (int b=blockIdx.x; b<nbatch; b+=gridDim.x){
    const int base=b*8;
    for (int idx=tid; idx<8*K; idx+=256){
      const int row=idx/K, k=idx-row*K, r=base+row;
      float v=0.f;
      if (r<rows){
        if(xPacked){
          const unsigned u=((const unsigned*)Xv)[(size_t)r*(K/2)+(k>>1)];
          v = (k&1) ? bfhi(u) : bflo(u);
        } else {
          v = Xv[(size_t)r*K+k];
        }
        if (mode==1){
          const float sv = partsIn ? redSQ[k]     : stS[k];
          const float qv = partsIn ? redSQ[128+k] : stQ[k];
          float mn=sv*invRows;
          float vr=fmaxf(qv*invRows-mn*mn,0.f);
          float sc=gam[k]*rsqrtf(vr+1e-5f);
          float sh=bet[k]-mn*sc;
          v=geluf(v*sc+sh);
        }
      }
      xls[idx]=v;
    }
    __syncthreads();
    #pragma unroll
    for (int rr=0;rr<8;rr++){
      const float* xp=&xls[rr*K+kh*KH];
      float acc=0.f;
      #pragma unroll
      for (int j=0;j<KH;j+=4){
        const float4 xv=*(const float4*)(xp+j);
        acc += wreg[j]*xv.x + wreg[j+1]*xv.y + wreg[j+2]*xv.z + wreg[j+3]*xv.w;
      }
      part[kh*1024 + rr*128 + c]=acc;
    }
    __syncthreads();
    if (Yp==nullptr){
      #pragma unroll
      for (int q=0;q<4;q++){
        const int r=kh*4+q, row=base+r;
        if (row<rows){
          float y=part[r*128+c]+part[1024+r*128+c];
          Y[row*128+c]=y;
          ls+=y; lq+=y*y;
        }
      }
      __syncthreads();
    } else {
      if constexpr (K==128){
        #pragma unroll
        for (int q=0;q<4;q++){
          const int r=kh*4+q, row=base+r;
          float y=0.f;
          if (row<rows){
            y=part[r*128+c]+part[1024+r*128+c];
            ls+=y; lq+=y*y;
          }
          xls[r*128+c]=y;
        }
        __syncthreads();
        for (int idx=tid; idx<512; idx+=256){
          const int r2=idx>>6, j=idx&63, row=base+r2;
          if(row<rows) Yp[(size_t)row*64+j]=packbf(xls[r2*128+2*j],xls[r2*128+2*j+1]);
        }
        __syncthreads();
      }
    }
  }
  if (outS){ atomicAdd(&outS[c],ls); atomicAdd(&outQ[c],lq); }
}

// dual-task rowgemm v6: bf16 MFMA (round-16 proven). 256 threads = 4 waves;
// M-tile 16 rows; wave owns 2 column-tiles (B fragments register-resident).
// Both inputs bf16-packed (bm packed in k_bondcyc since round-20).
struct RGDual {
  const float* x0; int rows0; int pk0; float inv0; const float* g0; const float* b0;
  unsigned* yp0; const float* parts0;
  const float* x1; int rows1; int pk1; float inv1; const float* g1; const float* b1;
  unsigned* yp1; const float* parts1;
  const float* W;
};
__global__ __launch_bounds__(256) void k_rowgemm_dual(RGDual D)
{
  const int tid=threadIdx.x;
  const int lane=tid&63, wave=tid>>6;
  const int l15=lane&15, lhi=lane>>4;
  __shared__ float scs0[128], shs0[128], scs1[128], shs1[128];
  {
    const int t=tid>>7, k=tid&127;
    const float* partsIn = t ? D.parts1 : D.parts0;
    float s=0.f,q=0.f;
    for(int j=0;j<64;j++){ s+=partsIn[j*256+k]; }
    for(int j=0;j<64;j++){ q+=partsIn[j*256+128+k]; }
    const float invRows = t ? D.inv1 : D.inv0;
    const float gam = (t ? D.g1 : D.g0)[k];
    const float bet = (t ? D.b1 : D.b0)[k];
    const float mn=s*invRows;
    const float vr=fmaxf(q*invRows-mn*mn,0.f);
    const float sc=gam*rsqrtf(vr+1e-5f);
    const float sh=bet-mn*sc;
    if(t){ scs1[k]=sc; shs1[k]=sh; } else { scs0[k]=sc; shs0[k]=sh; }
  }
  // B fragments (W = Wl, 64KB, L2-resident): load once per block.
  bf16x8 breg[2][4];
  #pragma unroll
  for(int ct=0;ct<2;ct++){
    const int col=(wave*2+ct)*16 + l15;
    #pragma unroll
    for(int ks=0;ks<4;ks++){
      const int kb=ks*32 + lhi*8;
      #pragma unroll
      for(int i=0;i<8;i++){
        breg[ct][ks][i]=__builtin_bit_cast(short, f2b(D.W[(size_t)(kb+i)*128+col]));
      }
    }
  }
  __syncthreads();
  __shared__ short xtile[16*136];   // pad 128->136: 16B-aligned rows, conflict-free A reads
  const int TB0=(D.rows0+15)>>4, TB1=(D.rows1+15)>>4;
  const int TBT=TB0+TB1;
  for (int gb=blockIdx.x; gb<TBT; gb+=gridDim.x){
    const int t1=(gb>=TB0);
    const int b = t1 ? gb-TB0 : gb;
    const float* Xv = t1 ? D.x1 : D.x0;
    const int rows  = t1 ? D.rows1 : D.rows0;
    const int xPacked = t1 ? D.pk1 : D.pk0;
    unsigned* Yp = t1 ? D.yp1 : D.yp0;
    const float* scs = t1 ? scs1 : scs0;
    const float* shs = t1 ? shs1 : shs0;
    const int base=b*16;
    // fill 16x128 bf16 tile (BN+gelu fused, pair-packed u32 stores)
    for (int idx=tid; idx<1024; idx+=256){
      const int row=idx>>6, kp=idx&63, k0=kp*2, r=base+row;
      float v0=0.f,v1=0.f;
      if (r<rows){
        if(xPacked){
          const unsigned u=((const unsigned*)Xv)[(size_t)r*64+kp];
          v0=bflo(u); v1=bfhi(u);
        } else {
          const float2 xv=((const float2*)(Xv+(size_t)r*128))[kp];
          v0=xv.x; v1=xv.y;
        }
        v0=geluf(v0*scs[k0]+shs[k0]);
        v1=geluf(v1*scs[k0+1]+shs[k0+1]);
      }
      ((unsigned*)xtile)[row*68+kp]=packbf(v0,v1);
    }
    __syncthreads();
    f32x4 acc0={0.f,0.f,0.f,0.f}, acc1={0.f,0.f,0.f,0.f};
    #pragma unroll
    for(int ks=0;ks<4;ks++){
      const bf16x8 afrag = *reinterpret_cast<const bf16x8*>(&xtile[l15*136 + ks*32 + lhi*8]);
      acc0=__builtin_amdgcn_mfma_f32_16x16x32_bf16(afrag,breg[0][ks],acc0,0,0,0);
      acc1=__builtin_amdgcn_mfma_f32_16x16x32_bf16(afrag,breg[1][ks],acc1,0,0,0);
    }
    // D write: lane col=(wave*2+ct)*16+l15, rows base+lhi*4+j; pack col pairs via shfl
    #pragma unroll
    for(int j=0;j<4;j++){
      const int row=base+lhi*4+j;
      const float ya=acc0[j];
      const float ya2=__shfl_xor(ya,1,64);
      if(((lane&1)==0) && row<rows)
        Yp[(size_t)row*64 + (wave*2+0)*8 + (l15>>1)]=packbf(ya,ya2);
      const float yb=acc1[j];
      const float yb2=__shfl_xor(yb,1,64);
      if(((lane&1)==0) && row<rows)
        Yp[(size_t)row*64 + (wave*2+1)*8 + (l15>>1)]=packbf(yb,yb2);
    }
    __syncthreads();
  }
}

__global__ __launch_bounds__(256) void k_table_T(const float* emb, const float* w1, const float* b1,
                                                 const float* w2, const float* b2, float* T)
{
  __shared__ float A[2048];
  const int tid=threadIdx.x;
  for (int idx=tid; idx<2048; idx+=256){
    const int half=idx>>10, rem=idx&1023, s=rem>>7, j=rem&127;
    float acc=0.f;
    for(int k=0;k<64;k++) acc += emb[s*64+k]*w1[(half*64+k)*128+j];
    A[idx]=acc;
  }
  __syncthreads();
  const int o=tid&127;
  for(int rr=tid>>7; rr<8; rr+=2){
    const int r=blockIdx.x*8+rr, s=r>>3, d=r&7;
    float acc=b2[o];
    for(int j=0;j<128;j++){
      float t1=A[s*128+j]+A[1024+d*128+j]+b1[j];
      acc+=t1*w2[j*128+o];
    }
    T[r*128+o]=acc;
  }
}

#define SCH 1024

__global__ __launch_bounds__(256) void k_edge_code(const int* sx, const int* src, const int* dst,
    const int* batch, unsigned char* code, unsigned short* gg, int* cnt64, int* ns,
    int* blockHist, int E)
{
  __shared__ int hist[64];
  __shared__ int gh[512];
  const int tid=threadIdx.x;
  if(tid<64) hist[tid]=0;
  for(int i=tid;i<512;i+=256) gh[i]=0;
  __syncthreads();
  const int base=blockIdx.x*SCH;
  #pragma unroll
  for(int u=0;u<SCH/256;u++){
    const int e=base+u*256+tid;
    if(e<E){
      const int s_=src[e], d_=dst[e];
      const int sc=sx[s_], dc=sx[d_];
      const int cd=sc*8+dc;
      code[e]=(unsigned char)cd;
      const int gb=batch[s_];
      gg[e]=(unsigned short)gb;
      atomicAdd(&hist[cd],1);
      atomicAdd(&ns[d_*8+sc],1);
      atomicAdd(&gh[gb],1);
    }
  }
  __syncthreads();
  if(tid<64){ int h=hist[tid]; if(h) atomicAdd(&cnt64[tid],h); }
  for(int i=tid;i<512;i+=256) blockHist[blockIdx.x*512+i]=gh[i];
}

__global__ __launch_bounds__(256) void k_gscan_col(int* blockHist, int* gtot, int NB){
  const int g=blockIdx.x;
  const int tid=threadIdx.x;
  __shared__ int sd[256];
  int run=0;
  for(int base=0;base<NB;base+=256){
    const int b=base+tid;
    const int v=(b<NB)?blockHist[(size_t)b*512+g]:0;
    sd[tid]=v; __syncthreads();
    for(int d=1;d<256;d<<=1){ int t=(tid>=d)?sd[tid-d]:0; __syncthreads(); sd[tid]+=t; __syncthreads(); }
    const int incl=sd[tid];
    const int tot=sd[255];
    if(b<NB) blockHist[(size_t)b*512+g]=run+incl-v;
    __syncthreads();
    run+=tot;
  }
  if(tid==0) gtot[g]=run;
}

// gscatter with inlined goff (integer scan -> exact). sortedG removed
// (pass2 derives group boundaries from gtot).
__global__ __launch_bounds__(256) void k_gscatter(const unsigned short* gg, const int* blockHist,
    const int* gtot, const unsigned char* code, const int* src, const int* dst,
    int* posE, unsigned long long* recP, int E){
  __shared__ int baseg[512];
  __shared__ int sg[512];
  const int tid=threadIdx.x;
  for(int i=tid;i<512;i+=256) sg[i]=gtot[i];
  __syncthreads();
  for(int d=1;d<512;d<<=1){
    int t0[2];
    for(int i=tid,j=0;i<512;i+=256,j++) t0[j]=(i>=d)?sg[i-d]:0;
    __syncthreads();
    for(int i=tid,j=0;i<512;i+=256,j++) sg[i]+=t0[j];
    __syncthreads();
  }
  for(int i=tid;i<512;i+=256) baseg[i]=blockHist[blockIdx.x*512+i]+sg[i]-gtot[i];
  __syncthreads();
  const int base=blockIdx.x*SCH;
  for(int i=tid;i<SCH;i+=256){
    const int e=base+i;
    if(e<E){
      const int g=gg[e];
      const int p=atomicAdd(&baseg[g],1);
      posE[e]=p;
      recP[p]=(unsigned long long)code[e] | ((unsigned long long)(unsigned)src[e]<<8)
            | ((unsigned long long)(unsigned)dst[e]<<32);
    }
  }
}

__global__ __launch_bounds__(256) void k_htable(const float* T, const int* cnt64,
    const float* g0, const float* beta0, const float* wattb, const float* wattc,
    float* h_table, float* abt, float* act, float* ea, int E)
{
  __shared__ float h[64*132];
  __shared__ float cw[64];
  const int tid=threadIdx.x;
  if(tid<64) cw[tid]=(float)cnt64[tid];
  __syncthreads();
  const int c=tid&127;
  const float invE=1.f/(float)E;
  float s=0.f,q=0.f;
  for(int r2=0;r2<64;r2++){ float v=T[r2*128+c]; float w=cw[r2]; s+=w*v; q+=w*v*v; }
  const float mn=s*invE, vr=fmaxf(q*invE-mn*mn,0.f);
  const float sc=g0[c]*rsqrtf(vr+1e-5f), sh=beta0[c]-mn*sc;
  for(int r=tid>>7; r<64; r+=2){
    float v=geluf(T[r*128+c]*sc+sh);
    h[r*132+c]=v;
    h_table[r*128+c]=v;
  }
  __syncthreads();
  if(tid<64){
    float sb=0.f,scc=0.f;
    for(int k=0;k<128;k++){ float hv=h[tid*132+k]; sb+=hv*wattb[k]; scc+=hv*wattc[k]; }
    const float ab_=lreluf(sb), ac_=lreluf(scc);
    abt[tid]=ab_; act[tid]=ac_;
    float mx=ac_;
    #pragma unroll
    for(int o=1;o<64;o<<=1) mx=fmaxf(mx,__shfl_xor(mx,o,64));
    ea[tid]=expf(ac_-mx);
  }
}

__global__ __launch_bounds__(256) void k_cycle_hist(const int* cseg, const int* cidx,
    const unsigned char* code, const int* posE, int* nsc, int* cntP, int M)
{
  const int base=blockIdx.x*1024+threadIdx.x;
  #pragma unroll
  for(int u=0;u<4;u++){
    const int m=base+u*256;
    if(m<M){
      const int e=cidx[m];
      atomicAdd(&nsc[cseg[m]*64 + (int)code[e]],1);
      atomicAdd(&cntP[posE[e]],1);
    }
  }
}

// Round-21 bondcyc v2 (proven): bond branch two-phase (weights computed once in
// Phase A via 8-lane shfl butterflies; Phase B 8 independent hWb loads x 8 FMA).
// Cyc branch = round-19 MFMA loop.
__global__ __launch_bounds__(256) void k_bondcyc(
    const int* nsc, const float* ea, const float* hWc, unsigned* ucm, float* parts2,
    int NC, int cycBlocks,
    const int* ns, const int* sx, const float* abt, const float* hWb,
    unsigned* bmp, float* parts1, int N)
{
  const int tid=threadIdx.x;
  __shared__ float sS[128], sQ[128];
  if(blockIdx.x<cycBlocks){
    // ------- cyc branch (MFMA, round-19 proven) -------
    const int lane=tid&63, wave=tid>>6;
    const int l15=lane&15, lhi=lane>>4;
    bf16x8 breg[2][2];
    #pragma unroll
    for(int ct=0;ct<2;ct++){
      const int col=(wave*2+ct)*16+l15;
      #pragma unroll
      for(int ks=0;ks<2;ks++){
        const int kb=ks*32+lhi*8;
        #pragma unroll
        for(int i=0;i<8;i++)
          breg[ct][ks][i]=__builtin_bit_cast(short, f2b(hWc[(size_t)(kb+i)*128+col]*ea[kb+i]));
      }
    }
    __shared__ float cnts[16*64];
    __shared__ short atile[16*72];   // pad 64->72 shorts: 2-way conflict (free)
    __shared__ float invcs[16];
    if(tid<128){ sS[tid]=0.f; sQ[tid]=0.f; }
    const float eaL=ea[lane];
    float ls0=0.f,lq0=0.f,ls1=0.f,lq1=0.f;
    const int ntile=(NC+15)>>4;
    for(int b=blockIdx.x;b<ntile;b+=cycBlocks){
      const int base=b*16;
      __syncthreads();  // protect cnts/atile from previous iteration readers
      for(int i=tid;i<1024;i+=256){
        const int seg=base+(i>>6);
        const float v=(seg<NC)?(float)nsc[(size_t)seg*64+(i&63)]:0.f;
        cnts[i]=v;
        atile[(i>>6)*72+(i&63)]=__builtin_bit_cast(short,f2b(v));
      }
      __syncthreads();
      // inline segsum (bit-exact: same per-row butterfly on exact float counts)
      #pragma unroll
      for(int rr2=0;rr2<4;rr2++){
        const int r=wave*4+rr2;
        const float n=cnts[r*64+lane];
        float S=n*eaL, C=n;
        #pragma unroll
        for(int o=1;o<64;o<<=1){ S+=__shfl_xor(S,o,64); C+=__shfl_xor(C,o,64); }
        if(lane==0) invcs[r]=(C>0.f&&S>0.f)?1.f/(S*C):0.f;
      }
      f32x4 acc0={0.f,0.f,0.f,0.f}, acc1={0.f,0.f,0.f,0.f};
      #pragma unroll
      for(int ks=0;ks<2;ks++){
        const bf16x8 afrag=*reinterpret_cast<const bf16x8*>(&atile[l15*72+ks*32+lhi*8]);
        acc0=__builtin_amdgcn_mfma_f32_16x16x32_bf16(afrag,breg[0][ks],acc0,0,0,0);
        acc1=__builtin_amdgcn_mfma_f32_16x16x32_bf16(afrag,breg[1][ks],acc1,0,0,0);
      }
      __syncthreads();  // invcs ready for all waves
      #pragma unroll
      for(int j=0;j<4;j++){
        const int r16=lhi*4+j, row=base+r16;
        const float iv=invcs[r16];
        const float y0=acc0[j]*iv;
        const float y1=acc1[j]*iv;
        ls0+=y0; lq0+=y0*y0; ls1+=y1; lq1+=y1*y1;
        const float y0b=__shfl_xor(y0,1,64);
        if(((lane&1)==0) && row<NC)
          ucm[(size_t)row*64 + (wave*2+0)*8 + (l15>>1)]=packbf(y0,y0b);
        const float y1b=__shfl_xor(y1,1,64);
        if(((lane&1)==0) && row<NC)
          ucm[(size_t)row*64 + (wave*2+1)*8 + (l15>>1)]=packbf(y1,y1b);
      }
    }
    __syncthreads();
    const int c0=(wave*2+0)*16+l15, c1=(wave*2+1)*16+l15;
    atomicAdd(&sS[c0],ls0); atomicAdd(&sQ[c0],lq0);
    atomicAdd(&sS[c1],ls1); atomicAdd(&sQ[c1],lq1);
    __syncthreads();
    if(tid<128){
      float* slot=&parts2[(size_t)(blockIdx.x&63)*256];
      atomicAdd(&slot[tid],sS[tid]); atomicAdd(&slot[128+tid],sQ[tid]);
    }
  } else {
    // ------- bond branch v2 (two-phase) -------
    const int base=(blockIdx.x-cycBlocks)*16;
    __shared__ float wts[16*8];
    __shared__ int dcls[16];
    if(tid<16){ const int n=base+tid; dcls[tid]=(n<N)?sx[n]:0; }
    __syncthreads();
    if(tid<128){
      // thread = node*8 + s ; 8-lane groups align within the wave
      const int node=tid>>3, s=tid&7;
      const int n=base+node;
      float v=0.f, a=-1e30f;
      if(n<N){
        v=(float)ns[n*8+s];
        if(v>0.f) a=abt[s*8+dcls[node]];
      }
      float cnt=v, mx=a;
      #pragma unroll
      for(int o=1;o<8;o<<=1){ cnt+=__shfl_xor(cnt,o,64); mx=fmaxf(mx,__shfl_xor(mx,o,64)); }
      const float ex=(v>0.f)? v*expf(a-mx) : 0.f;
      float ssum=ex;
      #pragma unroll
      for(int o=1;o<8;o<<=1) ssum+=__shfl_xor(ssum,o,64);
      float w=0.f;
      if(cnt>0.f){ const float inv=1.f/(ssum*cnt); w=ex*inv; }
      wts[tid]=w;
    }
    __syncthreads();
    const int c=tid&127, grp=tid>>7;
    float ls=0.f,lq=0.f;
    #pragma unroll
    for(int i=0;i<8;i++){
      const int node=grp*8+i;
      const int n=base+node;
      if(n>=N) break;   // wave-uniform
      const int d=dcls[node];
      float y=0.f;
      #pragma unroll
      for(int s=0;s<8;s++){
        const float w=wts[node*8+s];
        if(w>0.f) y += w*hWb[(s*8+d)*128+c];
      }
      const float y2=__shfl_xor(y,1,64);
      if((c&1)==0) bmp[(size_t)n*64+(c>>1)]=packbf(y,y2);
      ls+=y; lq+=y*y;
    }
    if(tid<128){ sS[tid]=0.f; sQ[tid]=0.f; }
    __syncthreads();
    atomicAdd(&sS[c],ls); atomicAdd(&sQ[c],lq);
    __syncthreads();
    if(tid<128){
      float* slot=&parts1[(size_t)(blockIdx.x&63)*256];
      atomicAdd(&slot[tid],sS[tid]); atomicAdd(&slot[128+tid],sQ[tid]);
    }
  }
}

__global__ __launch_bounds__(256) void k_scan_block(const int* cntP, int* blkSum, int E){
  __shared__ int sd[256];
  const int tid=threadIdx.x, base=blockIdx.x*1024;
  int s=0;
  for(int q=0;q<4;q++){ int i=base+tid*4+q; if(i<E) s+=cntP[i]; }
  sd[tid]=s; __syncthreads();
  for(int d=1;d<256;d<<=1){ int t=(tid>=d)?sd[tid-d]:0; __syncthreads(); sd[tid]+=t; __syncthreads(); }
  if(tid==255) blkSum[blockIdx.x]=sd[255];
}

__global__ __launch_bounds__(256) void k_scan_mid(const int* blkSum, int* blkOff, int nb){
  __shared__ int sd[1024];
  const int tid=threadIdx.x;
  for(int i=tid;i<1024;i+=256) sd[i]=(i<nb)?blkSum[i]:0;
  __syncthreads();
  for(int d=1;d<1024;d<<=1){
    int t[4];
    for(int i=tid,j=0;i<1024;i+=256,j++) t[j]=(i>=d)?sd[i-d]:0;
    __syncthreads();
    for(int i=tid,j=0;i<1024;i+=256,j++) sd[i]+=t[j];
    __syncthreads();
  }
  for(int i=tid;i<nb;i+=256) blkOff[i]=sd[i]-blkSum[i];
}

__global__ __launch_bounds__(256) void k_scan_write(const int* cntP, const int* blkOff,
                                                    int* offP, int E, int M){
  __shared__ int sd[256];
  const int tid=threadIdx.x, base=blockIdx.x*1024;
  int v[4]; int s=0;
  for(int q=0;q<4;q++){ int i=base+tid*4+q; v[q]=(i<E)?cntP[i]:0; s+=v[q]; }
  sd[tid]=s; __syncthreads();
  for(int d=1;d<256;d<<=1){ int t=(tid>=d)?sd[tid-d]:0; __syncthreads(); sd[tid]+=t; __syncthreads(); }
  int run=blkOff[blockIdx.x]+sd[tid]-s;
  for(int q=0;q<4;q++){ int i=base+tid*4+q; if(i<E) offP[i]=run; run+=v[q]; }
  if(blockIdx.x==0&&tid==0) offP[E]=M;
}

__global__ __launch_bounds__(256) void k_place(const int* cseg, const int* cidx, const int* posE,
                                               const int* offP, int* cursor, int* entrySeg, int M){
  const int base=blockIdx.x*1024+threadIdx.x;
  #pragma unroll
  for(int u=0;u<4;u++){
    const int m=base+u*256;
    if(m<M){
      const int p=posE[cidx[m]];
      const int pos=offP[p]+atomicAdd(&cursor[p],1);
      entrySeg[pos]=cseg[m];
    }
  }
}

// pass1: gather + stats + bf16 vbuf store. Persistent 2048 blocks; each wave owns a
// CONTIGUOUS edge range (round-4 structure, proven). The sequential packbf store
// (256 B/edge, streaming) hides under the gather latency; pass2 then never gathers.
__global__ __launch_bounds__(256) void k_pass1_store(const unsigned long long* recP,
    const float* eLt, const unsigned* ubond, const unsigned* ucyc,
    const int* offP, const int* entrySeg, unsigned* vbuf, float* parts,
    int E, int upx)
{
  const int tid=threadIdx.x;
  const int lane=tid&63, wave=tid>>6;
  const int xcd=blockIdx.x&7;
  const int wix=(blockIdx.x>>3)*4+wave;   // 0..1023 within xcd
  const int NU=(E+15)>>4;
  int u0=xcd*upx + (int)(((long long)wix*(long long)upx)>>10);
  int u1=xcd*upx + (int)(((long long)(wix+1)*(long long)upx)>>10);
  if(u0>NU)u0=NU; if(u1>NU)u1=NU;
  int e=u0*16; const int e1=(u1*16<E)?u1*16:E;
  float lsx=0.f,lsy=0.f,lqx=0.f,lqy=0.f;
  while(e<e1){
    int nv=e1-e; if(nv>64)nv=64;
    const int t=e+((lane<nv)?lane:(nv-1));
    const unsigned long long r0=recP[t];
    const unsigned rlo=(unsigned)r0, rhi=(unsigned)(r0>>32);
    const int oa0=offP[t], ob0=offP[t+1];
    int i=0;
    for(; i+8<=nv; i+=8){
      unsigned lo[8],hi[8]; int a[8],b[8];
      #pragma unroll
      for(int q=0;q<8;q++){
        lo[q]=(unsigned)__builtin_amdgcn_readlane((int)rlo,i+q);
        hi[q]=(unsigned)__builtin_amdgcn_readlane((int)rhi,i+q);
        a[q]=__builtin_amdgcn_readlane(oa0,i+q);
        b[q]=__builtin_amdgcn_readlane(ob0,i+q);
      }
      float2 ea[8]; unsigned ub[8],ud[8];
      #pragma unroll
      for(int q=0;q<8;q++){
        ea[q]=((const float2*)(eLt+(size_t)(lo[q]&0xFFu)*128))[lane];
        ub[q]=ubond[(size_t)(lo[q]>>8)*64+lane];
        ud[q]=ubond[(size_t)hi[q]*64+lane];
      }
      #pragma unroll
      for(int q=0;q<8;q++){
        float x=ea[q].x+bflo(ub[q])+bflo(ud[q]);
        float y=ea[q].y+bfhi(ub[q])+bfhi(ud[q]);
        for(int j=a[q];j<b[q];j++){
          const unsigned w=ucyc[(size_t)entrySeg[j]*64+lane];
          x+=bflo(w); y+=bfhi(w);
        }
        lsx+=x; lqx+=x*x; lsy+=y; lqy+=y*y;
        vbuf[(size_t)(e+i+q)*64+lane]=packbf(x,y);
      }
    }
    for(; i<nv; i++){
      const unsigned lo=(unsigned)__builtin_amdgcn_readlane((int)rlo,i);
      const unsigned hi=(unsigned)__builtin_amdgcn_readlane((int)rhi,i);
      const int a=__builtin_amdgcn_readlane(oa0,i);
      const int b=__builtin_amdgcn_readlane(ob0,i);
      const float2 ea2=((const float2*)(eLt+(size_t)(lo&0xFFu)*128))[lane];
      const unsigned ub=ubond[(size_t)(lo>>8)*64+lane];
      const unsigned ud=ubond[(size_t)hi*64+lane];
      float x=ea2.x+bflo(ub)+bflo(ud);
      float y=ea2.y+bfhi(ub)+bfhi(ud);
      for(int j=a;j<b;j++){
        const unsigned w=ucyc[(size_t)entrySeg[j]*64+lane];
        x+=bflo(w); y+=bfhi(w);
      }
      lsx+=x; lqx+=x*x; lsy+=y; lqy+=y*y;
      vbuf[(size_t)(e+i)*64+lane]=packbf(x,y);
    }
    e+=nv;
  }
  __shared__ float sS[128], sQ[128];
  if(tid<128){ sS[tid]=0.f; sQ[tid]=0.f; }
  __syncthreads();
  const int c0=lane*2;
  atomicAdd(&sS[c0],lsx); atomicAdd(&sS[c0+1],lsy);
  atomicAdd(&sQ[c0],lqx); atomicAdd(&sQ[c0+1],lqy);
  __syncthreads();
  if(tid<128){
    float* slot=&parts[(size_t)(blockIdx.x&63)*256];
    atomicAdd(&slot[tid],sS[tid]); atomicAdd(&slot[128+tid],sQ[tid]);
  }
}

// pass2 v4: round-18's proven group-segment structure (boundaries from gtot scan,
// one-row-per-lane 4B loads, ONE atomic flush per group) with the main batch
// deepened 16->32 (32x4B = 128 B/lane in flight; round-22's half-wave uint2
// variant regressed via doubled atomics + lower occupancy and was reverted).
__global__ __launch_bounds__(256) void k_pass2_stream(const unsigned* vbuf1,
    const int* gtot, const float* parts,
    const float* g3, const float* beta3, float* gsum, int E)
{
  __shared__ float sSQ[256];
  __shared__ int sg[512];
  __shared__ int goffL[513];
  const int tid=threadIdx.x;
  {
    float s=0.f;
    #pragma unroll 8
    for(int k=0;k<64;k++) s+=parts[k*256+tid];
    sSQ[tid]=s;
  }
  for(int i=tid;i<512;i+=256) sg[i]=gtot[i];
  __syncthreads();
  for(int d=1;d<512;d<<=1){
    int t0[2];
    for(int i=tid,j=0;i<512;i+=256,j++) t0[j]=(i>=d)?sg[i-d]:0;
    __syncthreads();
    for(int i=tid,j=0;i<512;i+=256,j++) sg[i]+=t0[j];
    __syncthreads();
  }
  for(int i=tid;i<512;i+=256) goffL[i]=sg[i]-gtot[i];
  if(tid==0) goffL[512]=E;
  __syncthreads();
  const int lane=tid&63, wave=tid>>6;
  const int c0=lane*2;
  const float invE=1.f/(float)E;
  float mn=sSQ[c0]*invE, vr=fmaxf(sSQ[128+c0]*invE-mn*mn,0.f);
  const float sc0=g3[c0]*rsqrtf(vr+1e-5f), sh0=beta3[c0]-mn*sc0;
  mn=sSQ[c0+1]*invE; vr=fmaxf(sSQ[128+c0+1]*invE-mn*mn,0.f);
  const float sc1=g3[c0+1]*rsqrtf(vr+1e-5f), sh1=beta3[c0+1]-mn*sc1;
  const int wix=blockIdx.x*4+wave;      // 0..8191
  int i0=(int)(((long long)wix*(long long)E)>>13);
  int i1=(int)(((long long)(wix+1)*(long long)E)>>13);
  if(i1>E)i1=E;
  if(i0>=i1) return;
  // binary search: largest g with goffL[g] <= i0
  int glo=0, ghi=512;
  while(glo+1<ghi){ const int gm=(glo+ghi)>>1; if(goffL[gm]<=i0) glo=gm; else ghi=gm; }
  int g=glo;
  int i=i0;
  while(i<i1){
    const int segEnd = (goffL[g+1]<i1)?goffL[g+1]:i1;
    if(segEnd<=i){ g++; continue; }
    float a0=0.f,a1=0.f;
    for(; i+32<=segEnd; i+=32){
      unsigned uq[32];
      #pragma unroll
      for(int q=0;q<32;q++) uq[q]=vbuf1[(size_t)(i+q)*64+lane];
      #pragma unroll
      for(int q=0;q<32;q++){
        a0+=geluf(fmaf(bflo(uq[q]),sc0,sh0));
        a1+=geluf(fmaf(bfhi(uq[q]),sc1,sh1));
      }
    }
    for(; i+4<=segEnd; i+=4){
      unsigned uq[4];
      #pragma unroll
      for(int q=0;q<4;q++) uq[q]=vbuf1[(size_t)(i+q)*64+lane];
      #pragma unroll
      for(int q=0;q<4;q++){
        a0+=geluf(fmaf(bflo(uq[q]),sc0,sh0));
        a1+=geluf(fmaf(bfhi(uq[q]),sc1,sh1));
      }
    }
    for(; i<segEnd; i++){
      const unsigned u=vbuf1[(size_t)i*64+lane];
      a0+=geluf(fmaf(bflo(u),sc0,sh0));
      a1+=geluf(fmaf(bfhi(u),sc1,sh1));
    }
    atomicAdd(&gsum[g*128+c0],a0); atomicAdd(&gsum[g*128+c0+1],a1);
    g++;
  }
}

__global__ __launch_bounds__(256) void k_out(const float* gw, const float* st4S, const float* st4Q,
    const float* g4, const float* beta4, const float* wout, void* out, const int* flag, int G)
{
  const int lane=threadIdx.x&63;
  const int r=blockIdx.x*4 + (threadIdx.x>>6);
  const float invG=1.f/(float)G;
  float a0=0.f,a1=0.f;
  #pragma unroll
  for(int h=0;h<2;h++){
    const int k=lane+64*h;
    const float mn=st4S[k]*invG;
    const float vr=fmaxf(st4Q[k]*invG-mn*mn,0.f);
    const float sc=g4[k]*rsqrtf(vr+1e-5f), sh=beta4[k]-mn*sc;
    const float v=geluf(gw[r*128+k]*sc+sh);
    a0+=v*wout[k*2+0]; a1+=v*wout[k*2+1];
  }
  for(int o=1;o<64;o<<=1){ a0+=__shfl_xor(a0,o,64); a1+=__shfl_xor(a1,o,64); }
  if(lane==0){
    if(*flag){ ((bf16*)out)[r*2+0]=f2b(a0); ((bf16*)out)[r*2+1]=f2b(a1); }
    else     { ((float*)out)[r*2+0]=a0;     ((float*)out)[r*2+1]=a1; }
  }
}

extern "C" void kernel_launch(void* const* d_in, const int* in_sizes, int n_in,
                              void* d_out, int out_size, void* d_ws, size_t ws_size,
                              hipStream_t stream)
{
  const int N  = in_sizes[0];
  const int E  = in_sizes[1]/2;
  const int M  = in_sizes[3];
  const int NC = 50000;
  const int G  = 512;

  const int* sub_x=(const int*)d_in[0];
  const int* src=(const int*)d_in[1];
  const int* dst=src+E;
  const int* batch=(const int*)d_in[2];
  const int* cseg=(const int*)d_in[3];
  const int* cidx=(const int*)d_in[4];

  char* ws=(char*)d_ws;
  size_t off=0;
  auto carve=[&](size_t bytes)->char*{ char* p=ws+off; off=(off+bytes+255)&~(size_t)255; return p; };

  size_t ftot=0;
  for(int i=0;i<28;i++) ftot += (size_t)in_sizes[5+i];
  float* stage=(float*)carve(ftot*4);
  float* fin[28];
  { size_t so=0; for(int i=0;i<28;i++){ fin[i]=stage+so; so+=(size_t)in_sizes[5+i]; } }
  const float *emb_f=fin[0], *w1_f=fin[1], *b1_f=fin[2], *w2_f=fin[3], *b2_f=fin[4],
              *g0_f=fin[5], *beta0_f=fin[6], *wattb_f=fin[7], *wb1_f=fin[8], *wb2_f=fin[9],
              *g1_f=fin[10], *beta1_f=fin[11], *wattc_f=fin[12], *wc1_f=fin[13], *wc2_f=fin[14],
              *g2_f=fin[15], *beta2_f=fin[16], *we1_f=fin[17], *we2_f=fin[18], *wl1_f=fin[19],
              *wl2_f=fin[20], *g3_f=fin[21], *beta3_f=fin[22], *wg1_f=fin[23], *wg2_f=fin[24],
              *g4_f=fin[25], *beta4_f=fin[26], *wout_f=fin[27];

  int* flag=(int*)carve(256);
  float* Wb =(float*)carve(65536);
  float* Wc =(float*)carve(65536);
  float* Wl =(float*)carve(65536);
  float* Wg =(float*)carve(65536);
  float* We =(float*)carve(65536);
  float* Wel=(float*)carve(65536);
  float* T      =(float*)carve(64*128*4);
  float* h_table=(float*)carve(64*128*4);
  float* hWb    =(float*)carve(64*128*4);
  float* hWc    =(float*)carve(64*128*4);
  float* eLt    =(float*)carve(64*128*4);
  float* abt=(float*)carve(256);
  float* act=(float*)carve(256);
  float* eaT=(float*)carve(256);
  unsigned* bmp =(unsigned*)carve((size_t)N*64*4);   // bond output, bf16-packed
  unsigned* ucm=(unsigned*)carve((size_t)NC*64*4);
  unsigned* ubond=(unsigned*)carve((size_t)N*64*4);
  unsigned* ucyc =(unsigned*)carve((size_t)NC*64*4);
  unsigned char* code=(unsigned char*)carve((size_t)E);
  unsigned short* gg=(unsigned short*)carve((size_t)E*2);
  int*   posE  =(int*)carve((size_t)E*4);
  unsigned long long* recP=(unsigned long long*)carve((size_t)E*8);
  int*   offP  =(int*)carve((size_t)(E+1)*4);
  int*   entrySeg=(int*)carve((size_t)M*4);
  int*   blkSum=(int*)carve(4096);
  int*   blkOff=(int*)carve(4096);
  int*   gtot  =(int*)carve(2048);
  const int NB=(E+SCH-1)/SCH;
  int*   blockHist=(int*)carve((size_t)NB*512*4);
  float* gw  =(float*)carve((size_t)G*128*4);

  const size_t zStart=off;
  int*   cnt64=(int*)carve(256);
  float* stats=(float*)carve(4096);
  float* st4S=stats+6*128, *st4Q=stats+7*128;
  float* parts1=(float*)carve(64*256*4);
  float* parts2=(float*)carve(64*256*4);
  float* parts3=(float*)carve(64*256*4);
  float* gsum=(float*)carve((size_t)G*128*4);
  int*   ns   =(int*)carve((size_t)N*8*4);
  int*   nsc  =(int*)carve((size_t)NC*64*4);
  int*   cntP =(int*)carve((size_t)E*4);
  int*   cursor=(int*)carve((size_t)E*4);
  const size_t zEnd=off;

  // big bf16 v-row buffer LAST (graph-sorted order)
  unsigned* vbuf=(unsigned*)carve((size_t)E*64*4);
  const int haveV = (off <= ws_size) ? 1 : 0;
  (void)n_in; (void)out_size;

  // 0. fused detect + convert + zero
  {
    ConvertArgs A{};
    for(int i=0;i<28;i++){ A.src[i]=d_in[5+i]; A.dst[i]=fin[i]; A.n[i]=in_sizes[5+i]; }
    k_convert<<<28+1024,256,0,stream>>>(A,(const unsigned int*)d_in[5],flag,
                                        (float*)(ws+zStart),(int)((zEnd-zStart)/4));
  }

  // 2. h pre-activation table
  k_table_T<<<8,256,0,stream>>>(emb_f,w1_f,b1_f,w2_f,b2_f,T);

  // 3. weight products
  {
    GemmTasks5 t{};
    t.X[0]=wb1_f; t.W[0]=wb2_f; t.Y[0]=Wb;
    t.X[1]=wc1_f; t.W[1]=wc2_f; t.Y[1]=Wc;
    t.X[2]=wl1_f; t.W[2]=wl2_f; t.Y[2]=Wl;
    t.X[3]=wg1_f; t.W[3]=wg2_f; t.Y[3]=Wg;
    t.X[4]=we1_f; t.W[4]=we2_f; t.Y[4]=We;
    k_rowgemm<128><<<dim3(16,5),256,0,stream>>>(t,128,0,0,nullptr,nullptr,0.f,nullptr,nullptr,nullptr,nullptr,nullptr,nullptr);
  }
  {
    GemmTasks5 t{};
    t.X[0]=We; t.W[0]=Wl; t.Y[0]=Wel;
    k_rowgemm<128><<<dim3(16,1),256,0,stream>>>(t,128,0,0,nullptr,nullptr,0.f,nullptr,nullptr,nullptr,nullptr,nullptr,nullptr);
  }

  // 4. edge codes + histograms; two-level sort (goff folded into gscatter)
  k_edge_code<<<NB,256,0,stream>>>(sub_x,src,dst,batch,code,gg,cnt64,ns,blockHist,E);
  k_gscan_col<<<512,256,0,stream>>>(blockHist,gtot,NB);
  k_gscatter<<<NB,256,0,stream>>>(gg,blockHist,gtot,code,src,dst,posE,recP,E);
  // 5. h table + attention logits + ea
  k_htable<<<1,256,0,stream>>>(T,cnt64,g0_f,beta0_f,wattb_f,wattc_f,h_table,abt,act,eaT,E);
  // 6. table products
  {
    GemmTasks5 t{};
    t.X[0]=h_table; t.W[0]=Wb;  t.Y[0]=hWb;
    t.X[1]=h_table; t.W[1]=Wc;  t.Y[1]=hWc;
    t.X[2]=h_table; t.W[2]=Wel; t.Y[2]=eLt;
    k_rowgemm<128><<<dim3(8,3),256,0,stream>>>(t,64,0,0,nullptr,nullptr,0.f,nullptr,nullptr,nullptr,nullptr,nullptr,nullptr);
  }
  // 7. cycle histograms (segment normalization folded into the fused cyc branch)
  k_cycle_hist<<<(M+1023)/1024,256,0,stream>>>(cseg,cidx,code,posE,nsc,cntP,M);
  // 8. bond + cycle branches fused in ONE dispatch (independent producers ->
  // machine-level overlap instead of stream serialization).
  {
    const int bondBlocks=(N+15)/16;
    k_bondcyc<<<2048+bondBlocks,256,0,stream>>>(nsc,eaT,hWc,ucm,parts2,NC,2048,
                                                ns,sub_x,abt,hWb,bmp,parts1,N);
  }
  // 9-11. bondL + cycL, one MFMA dispatch, unified balanced tile pool (both
  // inputs bf16-packed).
  {
    RGDual D{};
    D.x0=(const float*)bmp;  D.rows0=N;  D.pk0=1; D.inv0=1.f/(float)N;  D.g0=g1_f; D.b0=beta1_f; D.yp0=ubond; D.parts0=parts1;
    D.x1=(const float*)ucm;  D.rows1=NC; D.pk1=1; D.inv1=1.f/(float)NC; D.g1=g2_f; D.b1=beta2_f; D.yp1=ucyc;  D.parts1=parts2;
    D.W=Wl;
    k_rowgemm_dual<<<2048,256,0,stream>>>(D);
  }
  // 12. CSR over sorted positions
  const int nb=(E+1023)/1024;
  k_scan_block<<<nb,256,0,stream>>>(cntP,blkSum,E);
  k_scan_mid<<<1,256,0,stream>>>(blkSum,blkOff,nb);
  k_scan_write<<<nb,256,0,stream>>>(cntP,blkOff,offP,E,M);
  k_place<<<(M+1023)/1024,256,0,stream>>>(cseg,cidx,posE,offP,cursor,entrySeg,M);
  // 13-14. hybrid: single gather pass (stats + bf16 store), then group-segment
  // stream pool (boundaries from gtot scan; 32-deep 4B batched loads).
  {
    const int NU=(E+15)/16;
    const int upx=(NU+7)/8;
    k_pass1_store<<<2048,256,0,stream>>>(recP,eLt,ubond,ucyc,offP,entrySeg,
                                         haveV?vbuf:(unsigned*)cursor,parts3,E,upx);
    k_pass2_stream<<<2048,256,0,stream>>>(vbuf,gtot,parts3,
                                          g3_f,beta3_f,gsum,E);
  }
  // 15. head
  {
    GemmTasks5 t{};
    t.X[0]=gsum; t.W[0]=Wg; t.Y[0]=gw;
    k_rowgemm<128><<<dim3(64,1),256,0,stream>>>(t,G,0,0,nullptr,nullptr,0.f,nullptr,nullptr,st4S,st4Q,nullptr,nullptr);
  }
  // 16. out
  k_out<<<G/4,256,0,stream>>>(gw,st4S,st4Q,g4_f,beta4_f,wout_f,d_out,flag,G);
}